// Round 8
// baseline (288.900 us; speedup 1.0000x reference)
//
#include <hip/hip_runtime.h>

#define Hh 51
#define TT 512
#define MR 2            // batch rows per block (A-rows 0 and 4)
#define NBLK 256        // 512 / MR -> one block per CU, all 256 CUs
#define BT 512          // 8 waves: 0-3 layer-1 (waves 1/2 alternate out-proj), 4-7 layer-2
#define SHR 80          // H row stride in fp16 elems (160B)
#define NIT 514         // 512 steps + 2 pipeline-drain iterations (even)
#define LOG2E 1.4426950408889634f

typedef _Float16 half8 __attribute__((ext_vector_type(8)));
typedef __attribute__((ext_vector_type(4))) float f32x4;

__device__ __forceinline__ float fexp2(float x){ return __builtin_amdgcn_exp2f(x); }
__device__ __forceinline__ float frcp(float x){ return __builtin_amdgcn_rcpf(x); }
__device__ __forceinline__ unsigned short h16bits(_Float16 h){
    union { _Float16 h; unsigned short u; } c; c.h = h; return c.u;
}
// pack float -> fp16 hi/lo pair in one uint (hi in low 16, lo in high 16)
__device__ __forceinline__ unsigned packhl(float v){
    _Float16 hi = (_Float16)v;
    _Float16 lo = (_Float16)(v - (float)hi);
    return (unsigned)h16bits(hi) | ((unsigned)h16bits(lo) << 16);
}

// LSTM update, gate inputs pre-scaled in the weights:
//   vg0 = -LOG2E*zi, vg1 = -LOG2E*zf, vg2 = 2*LOG2E*zg, vg3 = -LOG2E*zo
// Parallel activation form (short serial chain); final op one fmaf.
__device__ __forceinline__ float lstm_update(float vg0, float vg1, float vg2,
                                             float vg3, float& cst){
    float ei = fexp2(vg0), ef = fexp2(vg1), eg = fexp2(vg2), eo = fexp2(vg3);
    float ii = frcp(1.f + ei);
    float ff = frcp(1.f + ef);
    float gg = fmaf(-2.f, frcp(1.f + eg), 1.f);   // tanh(zg)
    float oo = frcp(1.f + eo);
    cst = fmaf(ff, cst, ii * gg);
    float r  = frcp(1.f + fexp2(2.f * LOG2E * cst));
    return fmaf(-2.f * oo, r, oo);                // oo * tanh(cst)
}

#define MFMAH(a,b,c) __builtin_amdgcn_mfma_f32_16x16x32_f16(a,b,c,0,0,0)

__global__ __launch_bounds__(BT, 2) void lstm2_fold(
    const float* __restrict__ input,   // [512,512]
    const float* __restrict__ W_ih1,   // [204]
    const float* __restrict__ W_hh1,   // [204,51]
    const float* __restrict__ b_ih1,
    const float* __restrict__ b_hh1,
    const float* __restrict__ W_ih2,   // [204,51]
    const float* __restrict__ W_hh2,   // [204,51]
    const float* __restrict__ b_ih2,
    const float* __restrict__ b_hh2,
    const float* __restrict__ W_lin,   // [51]
    const float* __restrict__ b_lin,   // [1]
    float* __restrict__ out)           // [512,512]
{
    __shared__ unsigned xsp[(TT+1)*MR];  // packed fp16 hi/lo x[t][m]
    __shared__ float ob[TT*MR];          // out[t][m]
    // h state, A-frag layout [m][k] fp16, double-buffered by parity.
    // Live A-rows: 0, 4. K-slots per row: 0..50 = h, 51 = 1.0, 52/53 = x_hi/x_lo, 54 = 1.0.
    __shared__ __align__(16) _Float16 H1[2][16*SHR];
    __shared__ __align__(16) _Float16 H2[2][16*SHR];

    const int tid  = threadIdx.x;
    const int wv   = tid >> 6;
    const int lane = tid & 63;
    const int quad = lane >> 4;
    const int n16  = lane & 15;
    const int row0 = blockIdx.x * MR;
    const bool g1  = (wv < 4);
    const int  w   = g1 ? wv : (wv - 4);       // wave index within group
    const int  l   = 13 * w + n16;             // hidden unit owned by this lane-column
    const bool valid = (n16 <= 12) && (l < Hh);
    const bool liveA = ((n16 & 11) == 0);      // n16 in {0,4}: the two live A-rows
    const bool updL  = (quad < MR) && valid;   // lanes doing the gate/state update
    const bool xw    = (wv == 0) && (n16 == 0) && (quad < MR);  // x-forward lanes
    const int  fo    = n16 * SHR + quad * 8;   // A-frag element offset (loop-invariant)
    const int  ho    = (quad * 4) * SHR + l;   // h store offset (rows 0 / 4)

    // ---- stage input rows as packed fp16 hi/lo (coalesced in t)
#pragma unroll
    for (int i = 0; i < MR; ++i) {
        int idx = i * BT + tid; int m = idx >> 9, t = idx & 511;
        xsp[t * MR + m] = packhl(input[(row0 + m) * TT + t]);
    }
    if (tid < MR) xsp[TT * MR + tid] = 0u;     // tail (x(512) read at n=511)
    // ---- zero h buffers (both parities; all rows)
    for (int i = tid; i < 2 * 16 * SHR / 2; i += BT) {
        ((int*)H1)[i] = 0; ((int*)H2)[i] = 0;
    }

    // ---- persistent weight B-fragments (fp16), gate-interleaved permutation:
    // tile gt (gate i,f,g,o), col c=n16  <->  weight row gt*51 + (13w+c)
    // Gate scale factors folded into weights/biases BEFORE fp16 rounding:
    //   i,f,o: -LOG2E; g: +2*LOG2E  (removes the mul feeding each exp2).
    // K-columns 51..54 carry the affine epilogue: [bias_hi, wih, wih, bias_lo]
    half8 z8 = {0,0,0,0,0,0,0,0};
    half8 B1[4][2];                // W_hh1 (+bias1/wih slots)  (group 1)
    half8 B2[4][2], B3[4][2];      // W_ih2 (+bias2), W_hh2 (group 2)
    half8 Bout[2];                 // W_lin (+blin) column (waves 1,2)
    const f32x4 zc = (f32x4){0.f,0.f,0.f,0.f};   // persistent zero accumulator seed
#pragma unroll
    for (int gt = 0; gt < 4; ++gt) {
        const float gs = (gt == 2) ? (2.f * LOG2E) : (-LOG2E);   // gate scale
        int jrow = gt * Hh + l;
        float bias = 0.f, wih = 0.f;
        if (valid) {
            bias = gs * (g1 ? (b_ih1[jrow] + b_hh1[jrow]) : (b_ih2[jrow] + b_hh2[jrow]));
            wih  = g1 ? (gs * W_ih1[jrow]) : 0.f;
        }
        _Float16 bhi = (_Float16)bias;
        _Float16 blo = (_Float16)(bias - (float)bhi);
        _Float16 wih_h = (_Float16)wih;
#pragma unroll
        for (int kt = 0; kt < 2; ++kt) {
            B1[gt][kt] = z8; B2[gt][kt] = z8; B3[gt][kt] = z8;
#pragma unroll
            for (int jj = 0; jj < 8; ++jj) {
                int k = kt * 32 + quad * 8 + jj;
                if (valid) {
                    if (g1) {
                        if (k < Hh)       B1[gt][kt][jj] = (_Float16)(gs * W_hh1[jrow * Hh + k]);
                        else if (k == 51) B1[gt][kt][jj] = bhi;
                        else if (k == 52 || k == 53) B1[gt][kt][jj] = wih_h;
                        else if (k == 54) B1[gt][kt][jj] = blo;
                    } else {
                        if (k < Hh) {
                            B2[gt][kt][jj] = (_Float16)(gs * W_ih2[jrow * Hh + k]);
                            B3[gt][kt][jj] = (_Float16)(gs * W_hh2[jrow * Hh + k]);
                        } else if (k == 51) B2[gt][kt][jj] = bhi;
                        else if (k == 54)   B2[gt][kt][jj] = blo;
                    }
                }
            }
        }
    }
    {
        float blf = b_lin[0];
        _Float16 blhi = (_Float16)blf;
        _Float16 bllo = (_Float16)(blf - (float)blhi);
#pragma unroll
        for (int kt = 0; kt < 2; ++kt) {
            Bout[kt] = z8;
#pragma unroll
            for (int jj = 0; jj < 8; ++jj) {
                int k = kt * 32 + quad * 8 + jj;
                if ((wv == 1 || wv == 2) && n16 == 0) {
                    if (k < Hh)       Bout[kt][jj] = (_Float16)W_lin[k];
                    else if (k == 51) Bout[kt][jj] = blhi;
                    else if (k == 54) Bout[kt][jj] = bllo;
                }
            }
        }
    }
    float cst = 0.f;   // cell state: quad0 lanes -> batch row 0, quad1 -> row 1 (unit l)

    // A-fragment registers persist; masked-out lanes keep zero.
    half8 f1a = z8, f1b = z8;      // h1 frags
    half8 f2a = z8, f2b = z8;      // h2 frags (g2 + out-proj waves)

    __syncthreads();
    // ---- constant K-slots (after zeroing): rows 0,4; both parities; x(0) into parity 1
    if (tid < MR) {
        int r = tid * 4 * SHR;
#pragma unroll
        for (int p = 0; p < 2; ++p) {
            H1[p][r + 51] = (_Float16)1.0f;  H1[p][r + 54] = (_Float16)1.0f;
            H2[p][r + 51] = (_Float16)1.0f;  H2[p][r + 54] = (_Float16)1.0f;
        }
        *(unsigned*)&H1[1][r + 52] = xsp[tid];   // x(0) hi/lo for step 0 (reads parity 1)
    }
    __syncthreads();

    // one pipeline step; pA/pB are compile-time literals at call sites.
    // Model: step = reads(~130) + MFMA pipe(~466) + activation tail + barrier.
    // Changes vs v5 (209.8us best):
    //  (a) out-proj alternates waves 1 (even n) / 2 (odd n) -> SIMD3 no longer
    //      the constant straggler (was L1+out on wave 3).
    //  (b) isolated T5: setprio(1) around g2's MFMA cluster so g2's MFMAs
    //      issue first and its activation hides under g1's late MFMAs,
    //      de-serializing the two acts on the shared trans pipe.
    auto stepfn = [&](int n, int pA, int pB) {
        if (g1) {
            const bool ow = (wv == 1 + pB);    // out-proj owner this step (parity-folded)
            if (ow && liveA) {                 // out-proj frags: h2(n-2)
                f2a = *(const half8*)&H2[pB][fo];
                f2b = *(const half8*)&H2[pB][fo + 32];
            }
            if (n < TT) {
                // ---- layer-1, time n: z1 = Whh1·[h1(n-1),1,x(n)]  (epilogue in K-slack)
                unsigned xn = xw ? xsp[(n + 1) * MR + quad] : 0u;   // x(n+1) forward
                if (liveA) {
                    f1a = *(const half8*)&H1[pA][fo];
                    f1b = *(const half8*)&H1[pA][fo + 32];
                }
                f32x4 ac[4];
#pragma unroll
                for (int gt = 0; gt < 4; ++gt) {
                    f32x4 a = MFMAH(f1a, B1[gt][0], zc);
                    a       = MFMAH(f1b, B1[gt][1], a);
                    ac[gt] = a;
                }
                if (updL) {
                    float h = lstm_update(ac[0][0], ac[1][0], ac[2][0], ac[3][0], cst);
                    H1[pB][ho] = (_Float16)h;
                }
                if (xw) *(unsigned*)&H1[pB][(quad * 4) * SHR + 52] = xn;
            }
            if (ow && n >= 2) {
                // out(n-2) = W_lin·h2(n-2) + blin   (bias in K-slack)
                f32x4 ao = MFMAH(f2a, Bout[0], zc);
                ao       = MFMAH(f2b, Bout[1], ao);
                if (n16 == 0 && quad < MR) ob[(n - 2) * MR + quad] = ao[0];
            }
        } else if (n >= 1 && n <= TT) {
            // ---- layer-2, time n-1: z2 = Whh2·h2(n-2) + Wih2·[h1(n-1),1]
            if (liveA) {
                f2a = *(const half8*)&H2[pB][fo];
                f2b = *(const half8*)&H2[pB][fo + 32];
                f1a = *(const half8*)&H1[pA][fo];
                f1b = *(const half8*)&H1[pA][fo + 32];
            }
            __builtin_amdgcn_s_setprio(1);
            float vg[4];
#pragma unroll
            for (int gt = 0; gt < 4; ++gt) {
                f32x4 m2 = MFMAH(f2a, B3[gt][0], zc);
                m2       = MFMAH(f2b, B3[gt][1], m2);
                f32x4 m1 = MFMAH(f1a, B2[gt][0], zc);
                m1       = MFMAH(f1b, B2[gt][1], m1);
                vg[gt] = m2[0] + m1[0];
            }
            __builtin_amdgcn_s_setprio(0);
            if (updL) {
                float h = lstm_update(vg[0], vg[1], vg[2], vg[3], cst);
                H2[pA][ho] = (_Float16)h;
            }
        }
        __syncthreads();   // publishes h1(n), x(n+1), h2(n-1) for iteration n+1
    };

    // unroll x2: parity literals fold all LDS addressing to base+constant
    for (int k2 = 0; k2 < NIT / 2; ++k2) {
        stepfn(2 * k2,     1, 0);
        stepfn(2 * k2 + 1, 0, 1);
    }

    // ---- flush outputs (coalesced in t)
#pragma unroll
    for (int i = 0; i < MR; ++i) {
        int idx = i * BT + tid; int m = idx >> 9, t = idx & 511;
        out[(row0 + m) * TT + t] = ob[t * MR + m];
    }
}

extern "C" void kernel_launch(void* const* d_in, const int* in_sizes, int n_in,
                              void* d_out, int out_size, void* d_ws, size_t ws_size,
                              hipStream_t stream) {
    const float* input = (const float*)d_in[0];
    const float* W_ih1 = (const float*)d_in[1];
    const float* W_hh1 = (const float*)d_in[2];
    const float* b_ih1 = (const float*)d_in[3];
    const float* b_hh1 = (const float*)d_in[4];
    const float* W_ih2 = (const float*)d_in[5];
    const float* W_hh2 = (const float*)d_in[6];
    const float* b_ih2 = (const float*)d_in[7];
    const float* b_hh2 = (const float*)d_in[8];
    const float* W_lin = (const float*)d_in[9];
    const float* b_lin = (const float*)d_in[10];
    float* out = (float*)d_out;

    hipLaunchKernelGGL(lstm2_fold, dim3(NBLK), dim3(BT), 0, stream,
                       input, W_ih1, W_hh1, b_ih1, b_hh1,
                       W_ih2, W_hh2, b_ih2, b_hh2, W_lin, b_lin, out);
}

// Round 9
// 265.073 us; speedup vs baseline: 1.0899x; 1.0899x over previous
//
#include <hip/hip_runtime.h>

#define Hh 51
#define TT 512
#define MR 2            // batch rows per block (A-rows 0 and 4)
#define NBLK 256        // 512 / MR -> one block per CU, all 256 CUs
#define BT 512          // 8 waves: 0-3 layer-1 (+wave3: out-proj), 4-7 layer-2
#define SHR 80          // H row stride in fp16 elems (160B)
#define NIT 514         // 512 steps + 2 pipeline-drain iterations (even)
#define LOG2E 1.4426950408889634f

typedef _Float16 half8 __attribute__((ext_vector_type(8)));
typedef __attribute__((ext_vector_type(4))) float f32x4;

__device__ __forceinline__ float fexp2(float x){ return __builtin_amdgcn_exp2f(x); }
__device__ __forceinline__ float frcp(float x){ return __builtin_amdgcn_rcpf(x); }
__device__ __forceinline__ unsigned short h16bits(_Float16 h){
    union { _Float16 h; unsigned short u; } c; c.h = h; return c.u;
}
// pack float -> fp16 hi/lo pair in one uint (hi in low 16, lo in high 16)
__device__ __forceinline__ unsigned packhl(float v){
    _Float16 hi = (_Float16)v;
    _Float16 lo = (_Float16)(v - (float)hi);
    return (unsigned)h16bits(hi) | ((unsigned)h16bits(lo) << 16);
}

// Activation tail with pre-computed exponentials and SCALED cell state
// cs = 2*LOG2E*c  (removes the 2L*c multiply from the c->h serial chain):
//   ii,ff,oo = sigmoid via rcp(1+e);  gg2 = 2L*tanh(zg) (constants folded)
//   cs' = ff*cs + ii*gg2;  h = oo*tanh(c) = fmaf(-2oo, rcp(1+exp2(cs')), oo)
__device__ __forceinline__ float lstm_post(float eg, float ei, float ef,
                                           float eo, float& cs){
    float ii  = frcp(1.f + ei);
    float ff  = frcp(1.f + ef);
    float gg2 = fmaf(-4.f * LOG2E, frcp(1.f + eg), 2.f * LOG2E);
    float oo  = frcp(1.f + eo);
    cs = fmaf(ff, cs, ii * gg2);
    float r = frcp(1.f + fexp2(cs));
    return fmaf(-2.f * oo, r, oo);
}

#define MFMAH(a,b,c) __builtin_amdgcn_mfma_f32_16x16x32_f16(a,b,c,0,0,0)

__global__ __launch_bounds__(BT, 2) void lstm2_fold(
    const float* __restrict__ input,   // [512,512]
    const float* __restrict__ W_ih1,   // [204]
    const float* __restrict__ W_hh1,   // [204,51]
    const float* __restrict__ b_ih1,
    const float* __restrict__ b_hh1,
    const float* __restrict__ W_ih2,   // [204,51]
    const float* __restrict__ W_hh2,   // [204,51]
    const float* __restrict__ b_ih2,
    const float* __restrict__ b_hh2,
    const float* __restrict__ W_lin,   // [51]
    const float* __restrict__ b_lin,   // [1]
    float* __restrict__ out)           // [512,512]
{
    __shared__ unsigned xsp[(TT+1)*MR];  // packed fp16 hi/lo x[t][m]
    __shared__ float ob[TT*MR];          // out[t][m]
    // h state, A-frag layout [m][k] fp16, double-buffered by parity.
    // Live A-rows: 0, 4. K-slots per row: 0..50 = h, 51 = 1.0, 52/53 = x_hi/x_lo, 54 = 1.0.
    __shared__ __align__(16) _Float16 H1[2][16*SHR];
    __shared__ __align__(16) _Float16 H2[2][16*SHR];

    const int tid  = threadIdx.x;
    const int wv   = tid >> 6;
    const int lane = tid & 63;
    const int quad = lane >> 4;
    const int n16  = lane & 15;
    const int row0 = blockIdx.x * MR;
    const bool g1  = (wv < 4);
    const bool w3  = (wv == 3);
    const int  w   = g1 ? wv : (wv - 4);       // wave index within group
    const int  l   = 13 * w + n16;             // hidden unit owned by this lane-column
    const bool valid = (n16 <= 12) && (l < Hh);
    const bool liveA = ((n16 & 11) == 0);      // n16 in {0,4}: the two live A-rows
    const bool updL  = (quad < MR) && valid;   // lanes doing the gate/state update
    const bool xw    = (wv == 0) && (n16 == 0) && (quad < MR);  // x-forward lanes
    const int  fo    = n16 * SHR + quad * 8;   // A-frag element offset (loop-invariant)
    const int  ho    = (quad * 4) * SHR + l;   // h store offset (rows 0 / 4)

    // ---- stage input rows as packed fp16 hi/lo (coalesced in t)
#pragma unroll
    for (int i = 0; i < MR; ++i) {
        int idx = i * BT + tid; int m = idx >> 9, t = idx & 511;
        xsp[t * MR + m] = packhl(input[(row0 + m) * TT + t]);
    }
    if (tid < MR) xsp[TT * MR + tid] = 0u;     // tail (x(512) read at n=511)
    // ---- zero h buffers (both parities; all rows)
    for (int i = tid; i < 2 * 16 * SHR / 2; i += BT) {
        ((int*)H1)[i] = 0; ((int*)H2)[i] = 0;
    }

    // ---- persistent weight B-fragments (fp16), gate-interleaved permutation:
    // tile gt (gate i,f,g,o), col c=n16  <->  weight row gt*51 + (13w+c)
    // Gate scale factors folded into weights/biases BEFORE fp16 rounding:
    //   i,f,o: -LOG2E; g: +2*LOG2E  (removes the mul feeding each exp2).
    // K-columns 51..54 carry the affine epilogue: [bias_hi, wih, wih, bias_lo]
    half8 z8 = {0,0,0,0,0,0,0,0};
    half8 B1[4][2];                // W_hh1 (+bias1/wih slots)  (group 1)
    half8 B2[4][2], B3[4][2];      // W_ih2 (+bias2), W_hh2 (group 2)
    half8 Bout[2];                 // W_lin (+blin) column (wave 3)
    const f32x4 zc = (f32x4){0.f,0.f,0.f,0.f};   // persistent zero accumulator seed
#pragma unroll
    for (int gt = 0; gt < 4; ++gt) {
        const float gs = (gt == 2) ? (2.f * LOG2E) : (-LOG2E);   // gate scale
        int jrow = gt * Hh + l;
        float bias = 0.f, wih = 0.f;
        if (valid) {
            bias = gs * (g1 ? (b_ih1[jrow] + b_hh1[jrow]) : (b_ih2[jrow] + b_hh2[jrow]));
            wih  = g1 ? (gs * W_ih1[jrow]) : 0.f;
        }
        _Float16 bhi = (_Float16)bias;
        _Float16 blo = (_Float16)(bias - (float)bhi);
        _Float16 wih_h = (_Float16)wih;
#pragma unroll
        for (int kt = 0; kt < 2; ++kt) {
            B1[gt][kt] = z8; B2[gt][kt] = z8; B3[gt][kt] = z8;
#pragma unroll
            for (int jj = 0; jj < 8; ++jj) {
                int k = kt * 32 + quad * 8 + jj;
                if (valid) {
                    if (g1) {
                        if (k < Hh)       B1[gt][kt][jj] = (_Float16)(gs * W_hh1[jrow * Hh + k]);
                        else if (k == 51) B1[gt][kt][jj] = bhi;
                        else if (k == 52 || k == 53) B1[gt][kt][jj] = wih_h;
                        else if (k == 54) B1[gt][kt][jj] = blo;
                    } else {
                        if (k < Hh) {
                            B2[gt][kt][jj] = (_Float16)(gs * W_ih2[jrow * Hh + k]);
                            B3[gt][kt][jj] = (_Float16)(gs * W_hh2[jrow * Hh + k]);
                        } else if (k == 51) B2[gt][kt][jj] = bhi;
                        else if (k == 54)   B2[gt][kt][jj] = blo;
                    }
                }
            }
        }
    }
    {
        float blf = b_lin[0];
        _Float16 blhi = (_Float16)blf;
        _Float16 bllo = (_Float16)(blf - (float)blhi);
#pragma unroll
        for (int kt = 0; kt < 2; ++kt) {
            Bout[kt] = z8;
#pragma unroll
            for (int jj = 0; jj < 8; ++jj) {
                int k = kt * 32 + quad * 8 + jj;
                if (w3 && n16 == 0) {
                    if (k < Hh)       Bout[kt][jj] = (_Float16)W_lin[k];
                    else if (k == 51) Bout[kt][jj] = blhi;
                    else if (k == 54) Bout[kt][jj] = bllo;
                }
            }
        }
    }
    float cst = 0.f;   // SCALED cell state cs = 2*LOG2E*c  (quad0->row0, quad1->row1)

    // A-fragment registers persist; masked-out lanes keep zero.
    half8 f1a = z8, f1b = z8;      // h1 frags
    half8 f2a = z8, f2b = z8;      // h2 frags (g2 + wave3-out)

    __syncthreads();
    // ---- constant K-slots (after zeroing): rows 0,4; both parities; x(0) into parity 1
    if (tid < MR) {
        int r = tid * 4 * SHR;
#pragma unroll
        for (int p = 0; p < 2; ++p) {
            H1[p][r + 51] = (_Float16)1.0f;  H1[p][r + 54] = (_Float16)1.0f;
            H2[p][r + 51] = (_Float16)1.0f;  H2[p][r + 54] = (_Float16)1.0f;
        }
        *(unsigned*)&H1[1][r + 52] = xsp[tid];   // x(0) hi/lo for step 0 (reads parity 1)
    }
    __syncthreads();

    // one pipeline step; pA/pB are compile-time literals at call sites.
    // v5 structure (champion, 209.8us). Lessons baked in: all LDS reads at step
    // start (r1); C-chained MFMA pairs kept (r4); NO setprio (r8: -16% in this
    // lockstep structure). New (r9): g-gate MFMAs first with immediate exp2 so
    // the longest act chain starts under the remaining gate MFMAs; scaled cell
    // state cs=2L*c removes one mul from the c->h chain.
    auto stepfn = [&](int n, int pA, int pB) {
        if (g1) {
            if (w3 && n >= 2) {                // out-proj frags: h2(n-2)
                if (liveA) {
                    f2a = *(const half8*)&H2[pB][fo];
                    f2b = *(const half8*)&H2[pB][fo + 32];
                }
            }
            if (n < TT) {
                // ---- layer-1, time n: z1 = Whh1·[h1(n-1),1,x(n)]  (epilogue in K-slack)
                unsigned xn = xw ? xsp[(n + 1) * MR + quad] : 0u;   // x(n+1) forward
                if (liveA) {
                    f1a = *(const half8*)&H1[pA][fo];
                    f1b = *(const half8*)&H1[pA][fo + 32];
                }
                // gate order g,i,f,o: start each exp2 as soon as its gate lands
                f32x4 a2 = MFMAH(f1a, B1[2][0], zc); a2 = MFMAH(f1b, B1[2][1], a2);
                float eg = fexp2(a2[0]);
                f32x4 a0 = MFMAH(f1a, B1[0][0], zc); a0 = MFMAH(f1b, B1[0][1], a0);
                float ei = fexp2(a0[0]);
                f32x4 a1 = MFMAH(f1a, B1[1][0], zc); a1 = MFMAH(f1b, B1[1][1], a1);
                float ef = fexp2(a1[0]);
                f32x4 a3 = MFMAH(f1a, B1[3][0], zc); a3 = MFMAH(f1b, B1[3][1], a3);
                float eo = fexp2(a3[0]);
                if (updL) {
                    float h = lstm_post(eg, ei, ef, eo, cst);
                    H1[pB][ho] = (_Float16)h;
                }
                if (xw) *(unsigned*)&H1[pB][(quad * 4) * SHR + 52] = xn;
            }
            if (w3 && n >= 2) {
                // out(n-2) = W_lin·h2(n-2) + blin   (bias in K-slack)
                f32x4 ao = MFMAH(f2a, Bout[0], zc);
                ao       = MFMAH(f2b, Bout[1], ao);
                if (n16 == 0 && quad < MR) ob[(n - 2) * MR + quad] = ao[0];
            }
        } else if (n >= 1 && n <= TT) {
            // ---- layer-2, time n-1: z2 = Whh2·h2(n-2) + Wih2·[h1(n-1),1]
            // Two independent 2-chains per gate + one add; f2 read first so its
            // chain starts earliest. Gate order g,i,f,o with immediate exp2.
            if (liveA) {
                f2a = *(const half8*)&H2[pB][fo];
                f2b = *(const half8*)&H2[pB][fo + 32];
                f1a = *(const half8*)&H1[pA][fo];
                f1b = *(const half8*)&H1[pA][fo + 32];
            }
            f32x4 m2, m1;
            m2 = MFMAH(f2a, B3[2][0], zc); m2 = MFMAH(f2b, B3[2][1], m2);
            m1 = MFMAH(f1a, B2[2][0], zc); m1 = MFMAH(f1b, B2[2][1], m1);
            float eg = fexp2(m2[0] + m1[0]);
            m2 = MFMAH(f2a, B3[0][0], zc); m2 = MFMAH(f2b, B3[0][1], m2);
            m1 = MFMAH(f1a, B2[0][0], zc); m1 = MFMAH(f1b, B2[0][1], m1);
            float ei = fexp2(m2[0] + m1[0]);
            m2 = MFMAH(f2a, B3[1][0], zc); m2 = MFMAH(f2b, B3[1][1], m2);
            m1 = MFMAH(f1a, B2[1][0], zc); m1 = MFMAH(f1b, B2[1][1], m1);
            float ef = fexp2(m2[0] + m1[0]);
            m2 = MFMAH(f2a, B3[3][0], zc); m2 = MFMAH(f2b, B3[3][1], m2);
            m1 = MFMAH(f1a, B2[3][0], zc); m1 = MFMAH(f1b, B2[3][1], m1);
            float eo = fexp2(m2[0] + m1[0]);
            if (updL) {
                float h = lstm_post(eg, ei, ef, eo, cst);
                H2[pA][ho] = (_Float16)h;
            }
        }
        __syncthreads();   // publishes h1(n), x(n+1), h2(n-1) for iteration n+1
    };

    // unroll x2: parity literals fold all LDS addressing to base+constant
    for (int k2 = 0; k2 < NIT / 2; ++k2) {
        stepfn(2 * k2,     1, 0);
        stepfn(2 * k2 + 1, 0, 1);
    }

    // ---- flush outputs (coalesced in t)
#pragma unroll
    for (int i = 0; i < MR; ++i) {
        int idx = i * BT + tid; int m = idx >> 9, t = idx & 511;
        out[(row0 + m) * TT + t] = ob[t * MR + m];
    }
}

extern "C" void kernel_launch(void* const* d_in, const int* in_sizes, int n_in,
                              void* d_out, int out_size, void* d_ws, size_t ws_size,
                              hipStream_t stream) {
    const float* input = (const float*)d_in[0];
    const float* W_ih1 = (const float*)d_in[1];
    const float* W_hh1 = (const float*)d_in[2];
    const float* b_ih1 = (const float*)d_in[3];
    const float* b_hh1 = (const float*)d_in[4];
    const float* W_ih2 = (const float*)d_in[5];
    const float* W_hh2 = (const float*)d_in[6];
    const float* b_ih2 = (const float*)d_in[7];
    const float* b_hh2 = (const float*)d_in[8];
    const float* W_lin = (const float*)d_in[9];
    const float* b_lin = (const float*)d_in[10];
    float* out = (float*)d_out;

    hipLaunchKernelGGL(lstm2_fold, dim3(NBLK), dim3(BT), 0, stream,
                       input, W_ih1, W_hh1, b_ih1, b_hh1,
                       W_ih2, W_hh2, b_ih2, b_hh2, W_lin, b_lin, out);
}